// Round 16
// baseline (2699.274 us; speedup 1.0000x reference)
//
#include <hip/hip_runtime.h>
#include <cmath>

typedef _Float16 f16;
typedef _Float16 f16x8 __attribute__((ext_vector_type(8)));
typedef _Float16 f16x4 __attribute__((ext_vector_type(4)));
typedef float f32x4 __attribute__((ext_vector_type(4)));
typedef unsigned long long u64;

#define H_DIM 1024
#define I_DIMM 256
#define B_DIM 64
#define T_DIM 256
#define K_DIM 1280
#define NBLK 128                  // blocks; each owns 8 h-cols
#define SLABSZ (NBLK * 64 * 8)    // one h slab, f16 elements (128 KB)
#define FSTRIDE 64                // flag padding: 64 u32 = 256 B per block

// Build W16[4096][1280] = fp16([Whh | Wih]) row-major. grid = 4096 blocks.
__global__ __launch_bounds__(256) void conv_w_kernel(const float* __restrict__ Whh,
                                                     const float* __restrict__ Wih,
                                                     f16* __restrict__ W16) {
    const int r = blockIdx.x;
    const int tid = threadIdx.x;
    const float* hh = Whh + (size_t)r * H_DIM;
    const float* ih = Wih + (size_t)r * I_DIMM;
    f16* dst = W16 + (size_t)r * K_DIM;
    for (int k = tid; k < K_DIM; k += 256)
        dst[k] = (f16)(k < H_DIM ? hh[k] : ih[k - H_DIM]);
}

// x fp32 -> fp16, vectorized 4-wide. n4 = total/4.
__global__ __launch_bounds__(256) void conv_x_kernel(const float* __restrict__ x,
                                                     f16* __restrict__ x16, int n4) {
    const int i = blockIdx.x * 256 + threadIdx.x;
    if (i < n4) {
        float4 v = ((const float4*)x)[i];
        f16x4 o;
        o[0] = (f16)v.x; o[1] = (f16)v.y; o[2] = (f16)v.z; o[3] = (f16)v.w;
        ((f16x4*)x16)[i] = o;
    }
}

// sigmoid / tanh via v_exp_f32 + v_rcp_f32 (exact identities)
__device__ __forceinline__ float fsig(float x) {
    return __builtin_amdgcn_rcpf(1.f + __builtin_amdgcn_exp2f(-1.442695041f * x));
}
__device__ __forceinline__ float ftanh(float x) {
    return 1.f - 2.f * __builtin_amdgcn_rcpf(1.f + __builtin_amdgcn_exp2f(2.885390082f * x));
}

// Persistent LSTM, both phases, 512 steps, one cooperative launch.
// Base = round-14 verified kernel (2.30 ms), sync structure unchanged
// (sync A after gpart, sync B after activations, wave-0 publish+drain+flag).
// ROUND-16 CHANGES (latency micro-cuts only):
//   (1) early flag sample issued before the x-part, tested after -> poll RT
//       hidden under x MFMAs when producers already arrived.
//   (2) own-chunk LDS shortcut: the chunk with pb == blk is read from h_lds
//       (stable between sync B(t) and sync A(t+1); equals slab content since
//       wave 0 published from it; zero-init covers step 0) and own flag is
//       excluded from the poll -> removes the own drain->flag RT and 1/16 of
//       LLC burst traffic.
__global__ __launch_bounds__(512, 1) void lstm_persistent(
    f16* __restrict__ hX,            // [2][NBLK][64][8] ping-pong slabs
    const f16* __restrict__ x16,     // [64][256][256]
    const f16* __restrict__ W16e,    // [4096][1280]
    const f16* __restrict__ W16d,    // [4096][1280]
    const float* __restrict__ enc_bih, const float* __restrict__ enc_bhh,
    const float* __restrict__ dec_bih, const float* __restrict__ dec_bhh,
    unsigned* __restrict__ flags)    // [NBLK*FSTRIDE], zeroed each call
{
    __shared__ __align__(16) f16 lds_w[2][40][64][8];   // 80 KB  [ct][chunk][lane][8]
    __shared__ float gpart[4][64][34];                  // 34.8 KB [kq][batch][gatecol]
    __shared__ __align__(16) f16 h_lds[64][8];          // 1 KB

    const int tid  = threadIdx.x;
    const int blk  = blockIdx.x;
    const int w    = tid >> 6;
    const int bh   = w >> 2;              // batch half (0: rows 0-31, 1: 32-63)
    const int kq   = w & 3;               // K quarter
    const int lane = tid & 63;
    const int n    = lane & 15;
    const int kg   = lane >> 4;
    const int kg8  = kg * 8;

    // this wave's producer-flag address for the poll (lanes mod 32 -> 32 blocks)
    const int pl    = lane & 31;
    const int p_idx = ((pl >> 2) * 16) + kq * 4 + (pl & 3);
    const unsigned* fpoll = &flags[p_idx * FSTRIDE];
    const bool fskip = (p_idx == blk);    // own flag: satisfied via LDS shortcut

    // W rows for this lane's two column-tiles (gate-col = ct*16 + n)
    int rW[2];
    #pragma unroll
    for (int ct = 0; ct < 2; ++ct) {
        const int gc = ct * 16 + n;
        rW[ct] = (gc >> 3) * H_DIM + blk * 8 + (gc & 7);
    }

    // activation-thread mapping: one (batch, col) per thread
    const int ab   = tid >> 3;
    const int aj   = tid & 7;
    const int acol = blk * 8 + aj;

    float c_reg = 0.f;                    // cell state, carries enc -> dec
    unsigned stepv = 0;                   // monotone barrier epoch

    // h_lds must be valid before the first burst (own-chunk shortcut):
    // step 0 reads h_init = 0. One element per thread (64*8 = 512).
    h_lds[tid >> 3][tid & 7] = (f16)0.f;

    #pragma unroll 1
    for (int phase = 0; phase < 2; ++phase) {
        const f16* W  = phase ? W16d : W16e;
        const float* bi = phase ? dec_bih : enc_bih;
        const float* bhp = phase ? dec_bhh : enc_bhh;

        float bsum[4];
        #pragma unroll
        for (int g = 0; g < 4; ++g)
            bsum[g] = bi[g * H_DIM + acol] + bhp[g * H_DIM + acol];

        // Stage W chunks: bh=0 waves stage iters 0..4, bh=1 waves iters 5..9.
        {
            const int it0 = bh * 5;
            #pragma unroll 1
            for (int i = 0; i < 5; ++i) {
                const int c = (it0 + i) * 4 + kq;
                #pragma unroll
                for (int ct = 0; ct < 2; ++ct)
                    *(f16x8*)&lds_w[ct][c][lane][0] =
                        *(const f16x8*)(W + (size_t)rW[ct] * K_DIM + c * 32 + kg8);
            }
        }
        __syncthreads();   // also covers h_lds zero-init visibility (phase 0)

        #pragma unroll 1
        for (int t = 0; t < T_DIM; ++t) {
            // slab parity: input = t&1 (t=0 reads slab 0 = h_init), output = ~t&1
            const f16* slab_in  = hX + (size_t)(t & 1) * SLABSZ;
            f16*       slab_out = hX + (size_t)((t + 1) & 1) * SLABSZ;
            const f16* xt = x16 + (size_t)t * I_DIMM;

            f32x4 acc[2][2];   // [ct][btl]
            #pragma unroll
            for (int ct = 0; ct < 2; ++ct)
                #pragma unroll
                for (int btl = 0; btl < 2; ++btl)
                    acc[ct][btl] = (f32x4){0.f, 0.f, 0.f, 0.f};

            // ---- early flag sample (RT hidden under the x-part below) ----
            unsigned vflag = __hip_atomic_load(fpoll, __ATOMIC_RELAXED,
                                               __HIP_MEMORY_SCOPE_AGENT);

            // ---- x-part (h-independent): overlaps producers' tail + poll ----
            #pragma unroll
            for (int it = 8; it < 10; ++it) {
                const int c  = it * 4 + kq;
                const int xo = c * 32 - 1024 + kg8;
                f16x8 wf0 = *(const f16x8*)&lds_w[0][c][lane][0];
                f16x8 wf1 = *(const f16x8*)&lds_w[1][c][lane][0];
                #pragma unroll
                for (int btl = 0; btl < 2; ++btl) {
                    const int btg = bh * 2 + btl;
                    f16x8 a = *(const f16x8*)(xt + (size_t)(n + 16 * btg) * (T_DIM * I_DIMM) + xo);
                    acc[0][btl] = __builtin_amdgcn_mfma_f32_16x16x32_f16(a, wf0, acc[0][btl], 0, 0, 0);
                    acc[1][btl] = __builtin_amdgcn_mfma_f32_16x16x32_f16(a, wf1, acc[1][btl], 0, 0, 0);
                }
            }

            // ---- per-wave poll: wait for THIS wave's producers (own excluded) ----
            if (!__all(fskip || (vflag >= stepv))) {
                while (true) {
                    vflag = __hip_atomic_load(fpoll, __ATOMIC_RELAXED,
                                              __HIP_MEMORY_SCOPE_AGENT);
                    if (__all(fskip || (vflag >= stepv))) break;
                    __builtin_amdgcn_s_sleep(1);
                }
            }

            // ---- h burst: 32 x 8B sc1 loads; own chunk (pb==blk) from LDS ----
            u64 hb[32];
            #pragma unroll
            for (int it = 0; it < 8; ++it) {
                const int pb = it * 16 + kq * 4 + kg;
                #pragma unroll
                for (int btl = 0; btl < 2; ++btl) {
                    const int btg = bh * 2 + btl;
                    if (pb == blk) {
                        // h_lds holds exactly the slab chunk this block published
                        hb[(it * 2 + btl) * 2 + 0] = *(const u64*)&h_lds[n + 16 * btg][0];
                        hb[(it * 2 + btl) * 2 + 1] = *(const u64*)&h_lds[n + 16 * btg][4];
                    } else {
                        const u64* p = (const u64*)slab_in + (((size_t)pb * 64 + n + 16 * btg) << 1);
                        hb[(it * 2 + btl) * 2 + 0] =
                            __hip_atomic_load(p,     __ATOMIC_RELAXED, __HIP_MEMORY_SCOPE_AGENT);
                        hb[(it * 2 + btl) * 2 + 1] =
                            __hip_atomic_load(p + 1, __ATOMIC_RELAXED, __HIP_MEMORY_SCOPE_AGENT);
                    }
                }
            }
            __builtin_amdgcn_sched_barrier(0);   // pin the whole burst before MFMAs

            // ---- h-part MFMAs ----
            #pragma unroll
            for (int it = 0; it < 8; ++it) {
                const int c = it * 4 + kq;
                f16x8 wf0 = *(const f16x8*)&lds_w[0][c][lane][0];
                f16x8 wf1 = *(const f16x8*)&lds_w[1][c][lane][0];
                #pragma unroll
                for (int btl = 0; btl < 2; ++btl) {
                    union { u64 u[2]; f16x8 v; } U;
                    U.u[0] = hb[(it * 2 + btl) * 2 + 0];
                    U.u[1] = hb[(it * 2 + btl) * 2 + 1];
                    acc[0][btl] = __builtin_amdgcn_mfma_f32_16x16x32_f16(U.v, wf0, acc[0][btl], 0, 0, 0);
                    acc[1][btl] = __builtin_amdgcn_mfma_f32_16x16x32_f16(U.v, wf1, acc[1][btl], 0, 0, 0);
                }
            }

            // partials: D row = (bh*2+btl)*16 + kg*4 + r, col = ct*16 + n
            #pragma unroll
            for (int ct = 0; ct < 2; ++ct)
                #pragma unroll
                for (int btl = 0; btl < 2; ++btl)
                    #pragma unroll
                    for (int r = 0; r < 4; ++r)
                        gpart[kq][(bh * 2 + btl) * 16 + kg * 4 + r][ct * 16 + n] = acc[ct][btl][r];
            __syncthreads();   // (A) also completes the block-wide flag view

            // ---- activations + state update: one (batch, col) per thread ----
            {
                float pre[4];
                #pragma unroll
                for (int g = 0; g < 4; ++g)
                    pre[g] = gpart[0][ab][g * 8 + aj] + gpart[1][ab][g * 8 + aj]
                           + gpart[2][ab][g * 8 + aj] + gpart[3][ab][g * 8 + aj] + bsum[g];
                const float i_ = fsig(pre[0]);
                const float f_ = fsig(pre[1]);
                const float g_ = ftanh(pre[2]);
                const float o_ = fsig(pre[3]);
                c_reg = f_ * c_reg + i_ * g_;
                h_lds[ab][aj] = (f16)(o_ * ftanh(c_reg));
            }
            __syncthreads();   // (B) h_lds complete; gpart reads done

            ++stepv;
            // ---- publish tail: wave 0 only; other waves run ahead ----
            if (w == 0) {
                const u64* src = (const u64*)&h_lds[lane][0];
                u64 v0 = src[0], v1 = src[1];
                u64* dst = (u64*)slab_out + (((size_t)blk * 64 + lane) << 1);
                __hip_atomic_store(dst,     v0, __ATOMIC_RELAXED, __HIP_MEMORY_SCOPE_AGENT);
                __hip_atomic_store(dst + 1, v1, __ATOMIC_RELAXED, __HIP_MEMORY_SCOPE_AGENT);
                // wave-0 write-through drain: chunk globally visible
                asm volatile("s_waitcnt vmcnt(0)" ::: "memory");
                if (lane == 0)
                    __hip_atomic_store(&flags[blk * FSTRIDE], stepv,
                                       __ATOMIC_RELAXED, __HIP_MEMORY_SCOPE_AGENT);
            }
            // next iteration's sync A rejoins wave 0 before any h_lds/gpart reuse
        }
    }
}

// Tail MLP: a = PReLU(additional @ fcc_W^T + fcc_b); out[b] = [dh, a] @ fc_W^T + fc_b
// Final dec h is slab 0 (last step t=255 odd -> out parity 0), block-major:
// dh[b][k] = hX[k>>3][b][k&7]
__global__ __launch_bounds__(256) void tail_kernel(
    const f16* __restrict__ hX,        // [NBLK][64][8] (slab 0)
    const float* __restrict__ addl,    // [64][128]
    const float* __restrict__ fccW,    // [256][128]
    const float* __restrict__ fccb,    // [256]
    const float* __restrict__ fcW,     // [1][1280]
    const float* __restrict__ fcb,     // [1]
    const float* __restrict__ prelu_a, // [1]
    float* __restrict__ out)           // [64]
{
    __shared__ float a_lds[256];
    __shared__ float red[256];
    const int b = blockIdx.x;
    const int t = threadIdx.x;

    float s = fccb[t];
    const float* wr = fccW + t * 128;
    const float* ar = addl + b * 128;
    #pragma unroll 4
    for (int k = 0; k < 128; ++k) s += ar[k] * wr[k];
    const float pa = *prelu_a;
    a_lds[t] = (s >= 0.f) ? s : pa * s;
    __syncthreads();

    float acc = 0.f;
    for (int k = t; k < 1024; k += 256)
        acc += (float)hX[((size_t)(k >> 3) * 64 + b) * 8 + (k & 7)] * fcW[k];
    acc += a_lds[t] * fcW[1024 + t];
    red[t] = acc;
    __syncthreads();
    for (int sft = 128; sft > 0; sft >>= 1) {
        if (t < sft) red[t] += red[t + sft];
        __syncthreads();
    }
    if (t == 0) out[b] = red[0] + fcb[0];
}

extern "C" void kernel_launch(void* const* d_in, const int* in_sizes, int n_in,
                              void* d_out, int out_size, void* d_ws, size_t ws_size,
                              hipStream_t stream)
{
    const float* x       = (const float*)d_in[0];
    const float* addl    = (const float*)d_in[1];
    const float* enc_Wih = (const float*)d_in[2];
    const float* enc_Whh = (const float*)d_in[3];
    const float* enc_bih = (const float*)d_in[4];
    const float* enc_bhh = (const float*)d_in[5];
    const float* dec_Wih = (const float*)d_in[6];
    const float* dec_Whh = (const float*)d_in[7];
    const float* dec_bih = (const float*)d_in[8];
    const float* dec_bhh = (const float*)d_in[9];
    const float* fcc_W   = (const float*)d_in[10];
    const float* fcc_b   = (const float*)d_in[11];
    const float* fc_W    = (const float*)d_in[12];
    const float* fc_b    = (const float*)d_in[13];
    const float* prelu_a = (const float*)d_in[14];

    char* wsb = (char*)d_ws;
    const size_t W16_BYTES  = (size_t)4 * H_DIM * K_DIM * sizeof(f16);   // 10.5 MB
    const size_t X16_BYTES  = (size_t)B_DIM * T_DIM * I_DIMM * sizeof(f16);
    const size_t SLAB_BYTES = (size_t)SLABSZ * sizeof(f16);              // 128 KB

    f16* W16e = (f16*)wsb;                      wsb += W16_BYTES;
    f16* W16d = (f16*)wsb;                      wsb += W16_BYTES;
    f16* x16  = (f16*)wsb;                      wsb += X16_BYTES;
    f16* hX   = (f16*)wsb;                      wsb += 2 * SLAB_BYTES;
    unsigned* flags = (unsigned*)wsb;

    // One-time (per call) conversions + state init.
    conv_w_kernel<<<4 * H_DIM, 256, 0, stream>>>(enc_Whh, enc_Wih, W16e);
    conv_w_kernel<<<4 * H_DIM, 256, 0, stream>>>(dec_Whh, dec_Wih, W16d);
    conv_x_kernel<<<(B_DIM * T_DIM * I_DIMM / 4 + 255) / 256, 256, 0, stream>>>(
        x, x16, B_DIM * T_DIM * I_DIMM / 4);
    hipMemsetAsync(hX, 0, SLAB_BYTES, stream);                    // slab 0 = h_init = 0
    hipMemsetAsync(flags, 0, NBLK * FSTRIDE * sizeof(unsigned), stream);

    // Persistent cooperative kernel: both LSTMs, 512 steps, one launch.
    {
        void* args[] = { &hX, &x16, &W16e, &W16d,
                         &enc_bih, &enc_bhh, &dec_bih, &dec_bhh, &flags };
        hipLaunchCooperativeKernel((void*)lstm_persistent, dim3(NBLK), dim3(512),
                                   args, 0, stream);
    }

    // Final dec h is slab 0 (t=255 odd -> out parity 0).
    tail_kernel<<<64, 256, 0, stream>>>(hX, addl, fcc_W, fcc_b, fc_W, fc_b,
                                        prelu_a, (float*)d_out);
}

// Round 17
// 2304.499 us; speedup vs baseline: 1.1713x; 1.1713x over previous
//
#include <hip/hip_runtime.h>
#include <cmath>

typedef _Float16 f16;
typedef _Float16 f16x8 __attribute__((ext_vector_type(8)));
typedef _Float16 f16x4 __attribute__((ext_vector_type(4)));
typedef float f32x4 __attribute__((ext_vector_type(4)));
typedef unsigned long long u64;

#define H_DIM 1024
#define I_DIMM 256
#define B_DIM 64
#define T_DIM 256
#define K_DIM 1280
#define NBLK 128                  // blocks; each owns 8 h-cols
#define SLABSZ (NBLK * 64 * 8)    // one h slab, f16 elements (128 KB)
#define FSTRIDE 64                // flag padding: 64 u32 = 256 B per block

// Build W16[4096][1280] = fp16([Whh | Wih]) row-major. grid = 4096 blocks.
__global__ __launch_bounds__(256) void conv_w_kernel(const float* __restrict__ Whh,
                                                     const float* __restrict__ Wih,
                                                     f16* __restrict__ W16) {
    const int r = blockIdx.x;
    const int tid = threadIdx.x;
    const float* hh = Whh + (size_t)r * H_DIM;
    const float* ih = Wih + (size_t)r * I_DIMM;
    f16* dst = W16 + (size_t)r * K_DIM;
    for (int k = tid; k < K_DIM; k += 256)
        dst[k] = (f16)(k < H_DIM ? hh[k] : ih[k - H_DIM]);
}

// x fp32 -> fp16, vectorized 4-wide. n4 = total/4.
__global__ __launch_bounds__(256) void conv_x_kernel(const float* __restrict__ x,
                                                     f16* __restrict__ x16, int n4) {
    const int i = blockIdx.x * 256 + threadIdx.x;
    if (i < n4) {
        float4 v = ((const float4*)x)[i];
        f16x4 o;
        o[0] = (f16)v.x; o[1] = (f16)v.y; o[2] = (f16)v.z; o[3] = (f16)v.w;
        ((f16x4*)x16)[i] = o;
    }
}

// sigmoid / tanh via v_exp_f32 + v_rcp_f32 (exact identities)
__device__ __forceinline__ float fsig(float x) {
    return __builtin_amdgcn_rcpf(1.f + __builtin_amdgcn_exp2f(-1.442695041f * x));
}
__device__ __forceinline__ float ftanh(float x) {
    return 1.f - 2.f * __builtin_amdgcn_rcpf(1.f + __builtin_amdgcn_exp2f(2.885390082f * x));
}

// Persistent LSTM, both phases, 512 steps, one cooperative launch.
// This is the round-14 verified configuration (2.30 ms) restored verbatim:
//   - 512 threads = 8 waves; wave = (bh batch-half, kq K-quarter)
//   - fence-free sc1 coherence: write-through publish + bypass loads
//   - padded per-block flags (256 B) — line-exclusive arrivals and polls
//   - block-major h slabs — producer owns 8 exclusive LLC lines
//   - per-wave 32-producer flag poll (ballot), no post-poll syncthreads
//   - branch-free 32x8B h burst pinned by sched_barrier(0) (1 LLC latency)
//   - x-part MFMAs before the poll (overlap producers' tail)
//   - wave-0 publish + per-wave vmcnt(0) drain + lane-0 flag store
// r15 (tail restructure) and r16 (burst shortcut) both regressed; the
// residual is the recurrence-serialized LLC round-trip chain x 512 steps.
__global__ __launch_bounds__(512, 1) void lstm_persistent(
    f16* __restrict__ hX,            // [2][NBLK][64][8] ping-pong slabs
    const f16* __restrict__ x16,     // [64][256][256]
    const f16* __restrict__ W16e,    // [4096][1280]
    const f16* __restrict__ W16d,    // [4096][1280]
    const float* __restrict__ enc_bih, const float* __restrict__ enc_bhh,
    const float* __restrict__ dec_bih, const float* __restrict__ dec_bhh,
    unsigned* __restrict__ flags)    // [NBLK*FSTRIDE], zeroed each call
{
    __shared__ __align__(16) f16 lds_w[2][40][64][8];   // 80 KB  [ct][chunk][lane][8]
    __shared__ float gpart[4][64][34];                  // 34.8 KB [kq][batch][gatecol]
    __shared__ __align__(16) f16 h_lds[64][8];          // 1 KB

    const int tid  = threadIdx.x;
    const int blk  = blockIdx.x;
    const int w    = tid >> 6;
    const int bh   = w >> 2;              // batch half (0: rows 0-31, 1: 32-63)
    const int kq   = w & 3;               // K quarter
    const int lane = tid & 63;
    const int n    = lane & 15;
    const int kg   = lane >> 4;
    const int kg8  = kg * 8;

    // this wave's producer-flag address for the poll (lanes mod 32 -> 32 blocks)
    const int pl   = lane & 31;
    const unsigned* fpoll = &flags[(((pl >> 2) * 16) + kq * 4 + (pl & 3)) * FSTRIDE];

    // W rows for this lane's two column-tiles (gate-col = ct*16 + n)
    int rW[2];
    #pragma unroll
    for (int ct = 0; ct < 2; ++ct) {
        const int gc = ct * 16 + n;
        rW[ct] = (gc >> 3) * H_DIM + blk * 8 + (gc & 7);
    }

    // activation-thread mapping: one (batch, col) per thread
    const int ab   = tid >> 3;
    const int aj   = tid & 7;
    const int acol = blk * 8 + aj;

    float c_reg = 0.f;                    // cell state, carries enc -> dec
    unsigned stepv = 0;                   // monotone barrier epoch

    #pragma unroll 1
    for (int phase = 0; phase < 2; ++phase) {
        const f16* W  = phase ? W16d : W16e;
        const float* bi = phase ? dec_bih : enc_bih;
        const float* bhp = phase ? dec_bhh : enc_bhh;

        float bsum[4];
        #pragma unroll
        for (int g = 0; g < 4; ++g)
            bsum[g] = bi[g * H_DIM + acol] + bhp[g * H_DIM + acol];

        // Stage W chunks: bh=0 waves stage iters 0..4, bh=1 waves iters 5..9.
        {
            const int it0 = bh * 5;
            #pragma unroll 1
            for (int i = 0; i < 5; ++i) {
                const int c = (it0 + i) * 4 + kq;
                #pragma unroll
                for (int ct = 0; ct < 2; ++ct)
                    *(f16x8*)&lds_w[ct][c][lane][0] =
                        *(const f16x8*)(W + (size_t)rW[ct] * K_DIM + c * 32 + kg8);
            }
        }
        __syncthreads();

        #pragma unroll 1
        for (int t = 0; t < T_DIM; ++t) {
            // slab parity: input = t&1 (t=0 reads slab 0 = h_init), output = ~t&1
            const f16* slab_in  = hX + (size_t)(t & 1) * SLABSZ;
            f16*       slab_out = hX + (size_t)((t + 1) & 1) * SLABSZ;
            const f16* xt = x16 + (size_t)t * I_DIMM;

            f32x4 acc[2][2];   // [ct][btl]
            #pragma unroll
            for (int ct = 0; ct < 2; ++ct)
                #pragma unroll
                for (int btl = 0; btl < 2; ++btl)
                    acc[ct][btl] = (f32x4){0.f, 0.f, 0.f, 0.f};

            // ---- x-part (h-independent): overlaps the producers' tail ----
            #pragma unroll
            for (int it = 8; it < 10; ++it) {
                const int c  = it * 4 + kq;
                const int xo = c * 32 - 1024 + kg8;
                f16x8 wf0 = *(const f16x8*)&lds_w[0][c][lane][0];
                f16x8 wf1 = *(const f16x8*)&lds_w[1][c][lane][0];
                #pragma unroll
                for (int btl = 0; btl < 2; ++btl) {
                    const int btg = bh * 2 + btl;
                    f16x8 a = *(const f16x8*)(xt + (size_t)(n + 16 * btg) * (T_DIM * I_DIMM) + xo);
                    acc[0][btl] = __builtin_amdgcn_mfma_f32_16x16x32_f16(a, wf0, acc[0][btl], 0, 0, 0);
                    acc[1][btl] = __builtin_amdgcn_mfma_f32_16x16x32_f16(a, wf1, acc[1][btl], 0, 0, 0);
                }
            }

            // ---- per-wave poll: wait for THIS wave's 32 producers ----
            while (true) {
                unsigned v = __hip_atomic_load(fpoll, __ATOMIC_RELAXED,
                                               __HIP_MEMORY_SCOPE_AGENT);
                if (__all(v >= stepv)) break;
                __builtin_amdgcn_s_sleep(1);
            }

            // ---- h burst: 16 fragments (32 x 8B sc1), block-major slab ----
            u64 hb[32];
            #pragma unroll
            for (int it = 0; it < 8; ++it) {
                const int pb = it * 16 + kq * 4 + kg;
                #pragma unroll
                for (int btl = 0; btl < 2; ++btl) {
                    const int btg = bh * 2 + btl;
                    const u64* p = (const u64*)slab_in + (((size_t)pb * 64 + n + 16 * btg) << 1);
                    hb[(it * 2 + btl) * 2 + 0] =
                        __hip_atomic_load(p,     __ATOMIC_RELAXED, __HIP_MEMORY_SCOPE_AGENT);
                    hb[(it * 2 + btl) * 2 + 1] =
                        __hip_atomic_load(p + 1, __ATOMIC_RELAXED, __HIP_MEMORY_SCOPE_AGENT);
                }
            }
            __builtin_amdgcn_sched_barrier(0);   // pin all 32 loads before MFMAs

            // ---- h-part MFMAs ----
            #pragma unroll
            for (int it = 0; it < 8; ++it) {
                const int c = it * 4 + kq;
                f16x8 wf0 = *(const f16x8*)&lds_w[0][c][lane][0];
                f16x8 wf1 = *(const f16x8*)&lds_w[1][c][lane][0];
                #pragma unroll
                for (int btl = 0; btl < 2; ++btl) {
                    union { u64 u[2]; f16x8 v; } U;
                    U.u[0] = hb[(it * 2 + btl) * 2 + 0];
                    U.u[1] = hb[(it * 2 + btl) * 2 + 1];
                    acc[0][btl] = __builtin_amdgcn_mfma_f32_16x16x32_f16(U.v, wf0, acc[0][btl], 0, 0, 0);
                    acc[1][btl] = __builtin_amdgcn_mfma_f32_16x16x32_f16(U.v, wf1, acc[1][btl], 0, 0, 0);
                }
            }

            // partials: D row = (bh*2+btl)*16 + kg*4 + r, col = ct*16 + n
            #pragma unroll
            for (int ct = 0; ct < 2; ++ct)
                #pragma unroll
                for (int btl = 0; btl < 2; ++btl)
                    #pragma unroll
                    for (int r = 0; r < 4; ++r)
                        gpart[kq][(bh * 2 + btl) * 16 + kg * 4 + r][ct * 16 + n] = acc[ct][btl][r];
            __syncthreads();   // (A) also completes the block-wide flag view

            // ---- activations + state update: one (batch, col) per thread ----
            {
                float pre[4];
                #pragma unroll
                for (int g = 0; g < 4; ++g)
                    pre[g] = gpart[0][ab][g * 8 + aj] + gpart[1][ab][g * 8 + aj]
                           + gpart[2][ab][g * 8 + aj] + gpart[3][ab][g * 8 + aj] + bsum[g];
                const float i_ = fsig(pre[0]);
                const float f_ = fsig(pre[1]);
                const float g_ = ftanh(pre[2]);
                const float o_ = fsig(pre[3]);
                c_reg = f_ * c_reg + i_ * g_;
                h_lds[ab][aj] = (f16)(o_ * ftanh(c_reg));
            }
            __syncthreads();   // (B) h_lds complete; gpart reads done

            ++stepv;
            // ---- publish tail: wave 0 only; other waves run ahead ----
            if (w == 0) {
                const u64* src = (const u64*)&h_lds[lane][0];
                u64 v0 = src[0], v1 = src[1];
                u64* dst = (u64*)slab_out + (((size_t)blk * 64 + lane) << 1);
                __hip_atomic_store(dst,     v0, __ATOMIC_RELAXED, __HIP_MEMORY_SCOPE_AGENT);
                __hip_atomic_store(dst + 1, v1, __ATOMIC_RELAXED, __HIP_MEMORY_SCOPE_AGENT);
                // wave-0 write-through drain: chunk globally visible
                asm volatile("s_waitcnt vmcnt(0)" ::: "memory");
                if (lane == 0)
                    __hip_atomic_store(&flags[blk * FSTRIDE], stepv,
                                       __ATOMIC_RELAXED, __HIP_MEMORY_SCOPE_AGENT);
            }
            // next iteration's sync A rejoins wave 0 before any h_lds/gpart reuse
        }
    }
}

// Tail MLP: a = PReLU(additional @ fcc_W^T + fcc_b); out[b] = [dh, a] @ fc_W^T + fc_b
// Final dec h is slab 0 (last step t=255 odd -> out parity 0), block-major:
// dh[b][k] = hX[k>>3][b][k&7]
__global__ __launch_bounds__(256) void tail_kernel(
    const f16* __restrict__ hX,        // [NBLK][64][8] (slab 0)
    const float* __restrict__ addl,    // [64][128]
    const float* __restrict__ fccW,    // [256][128]
    const float* __restrict__ fccb,    // [256]
    const float* __restrict__ fcW,     // [1][1280]
    const float* __restrict__ fcb,     // [1]
    const float* __restrict__ prelu_a, // [1]
    float* __restrict__ out)           // [64]
{
    __shared__ float a_lds[256];
    __shared__ float red[256];
    const int b = blockIdx.x;
    const int t = threadIdx.x;

    float s = fccb[t];
    const float* wr = fccW + t * 128;
    const float* ar = addl + b * 128;
    #pragma unroll 4
    for (int k = 0; k < 128; ++k) s += ar[k] * wr[k];
    const float pa = *prelu_a;
    a_lds[t] = (s >= 0.f) ? s : pa * s;
    __syncthreads();

    float acc = 0.f;
    for (int k = t; k < 1024; k += 256)
        acc += (float)hX[((size_t)(k >> 3) * 64 + b) * 8 + (k & 7)] * fcW[k];
    acc += a_lds[t] * fcW[1024 + t];
    red[t] = acc;
    __syncthreads();
    for (int sft = 128; sft > 0; sft >>= 1) {
        if (t < sft) red[t] += red[t + sft];
        __syncthreads();
    }
    if (t == 0) out[b] = red[0] + fcb[0];
}

extern "C" void kernel_launch(void* const* d_in, const int* in_sizes, int n_in,
                              void* d_out, int out_size, void* d_ws, size_t ws_size,
                              hipStream_t stream)
{
    const float* x       = (const float*)d_in[0];
    const float* addl    = (const float*)d_in[1];
    const float* enc_Wih = (const float*)d_in[2];
    const float* enc_Whh = (const float*)d_in[3];
    const float* enc_bih = (const float*)d_in[4];
    const float* enc_bhh = (const float*)d_in[5];
    const float* dec_Wih = (const float*)d_in[6];
    const float* dec_Whh = (const float*)d_in[7];
    const float* dec_bih = (const float*)d_in[8];
    const float* dec_bhh = (const float*)d_in[9];
    const float* fcc_W   = (const float*)d_in[10];
    const float* fcc_b   = (const float*)d_in[11];
    const float* fc_W    = (const float*)d_in[12];
    const float* fc_b    = (const float*)d_in[13];
    const float* prelu_a = (const float*)d_in[14];

    char* wsb = (char*)d_ws;
    const size_t W16_BYTES  = (size_t)4 * H_DIM * K_DIM * sizeof(f16);   // 10.5 MB
    const size_t X16_BYTES  = (size_t)B_DIM * T_DIM * I_DIMM * sizeof(f16);
    const size_t SLAB_BYTES = (size_t)SLABSZ * sizeof(f16);              // 128 KB

    f16* W16e = (f16*)wsb;                      wsb += W16_BYTES;
    f16* W16d = (f16*)wsb;                      wsb += W16_BYTES;
    f16* x16  = (f16*)wsb;                      wsb += X16_BYTES;
    f16* hX   = (f16*)wsb;                      wsb += 2 * SLAB_BYTES;
    unsigned* flags = (unsigned*)wsb;

    // One-time (per call) conversions + state init.
    conv_w_kernel<<<4 * H_DIM, 256, 0, stream>>>(enc_Whh, enc_Wih, W16e);
    conv_w_kernel<<<4 * H_DIM, 256, 0, stream>>>(dec_Whh, dec_Wih, W16d);
    conv_x_kernel<<<(B_DIM * T_DIM * I_DIMM / 4 + 255) / 256, 256, 0, stream>>>(
        x, x16, B_DIM * T_DIM * I_DIMM / 4);
    hipMemsetAsync(hX, 0, SLAB_BYTES, stream);                    // slab 0 = h_init = 0
    hipMemsetAsync(flags, 0, NBLK * FSTRIDE * sizeof(unsigned), stream);

    // Persistent cooperative kernel: both LSTMs, 512 steps, one launch.
    {
        void* args[] = { &hX, &x16, &W16e, &W16d,
                         &enc_bih, &enc_bhh, &dec_bih, &dec_bhh, &flags };
        hipLaunchCooperativeKernel((void*)lstm_persistent, dim3(NBLK), dim3(512),
                                   args, 0, stream);
    }

    // Final dec h is slab 0 (t=255 odd -> out parity 0).
    tail_kernel<<<64, 256, 0, stream>>>(hX, addl, fcc_W, fcc_b, fc_W, fc_b,
                                        prelu_a, (float*)d_out);
}